// Round 9
// baseline (477.492 us; speedup 1.0000x reference)
//
#include <hip/hip_runtime.h>
#include <hip/hip_bf16.h>
#include <hip/hip_fp16.h>

#define N_USERS 40000
#define N_ITEMS 60000
#define N_NODES 100000
#define NPAD 100032  // padded to 64-row blocks for MFMA transform
#define DIM 64
#define NNZ 1200000
#define BATCH 1024
#define NEG_SLOPE 0.2f

typedef _Float16 half8 __attribute__((ext_vector_type(8)));
typedef float f32x4 __attribute__((ext_vector_type(4)));

// ---------------- CSR build ----------------

__global__ void k_zero(int* __restrict__ p, int n) {
    int i = blockIdx.x * blockDim.x + threadIdx.x;
    if (i < n) p[i] = 0;
}

// count + per-edge intra-row rank (pos). One atomic per edge, total 1.2M.
__global__ void k_count(const int* __restrict__ rows, int* __restrict__ counts,
                        int* __restrict__ pos) {
    int e = blockIdx.x * blockDim.x + threadIdx.x;
    if (e < NNZ) pos[e] = atomicAdd(&counts[rows[e]], 1);
}

// per-chunk (1024 elems) sums
__global__ void k_scanA(const int* __restrict__ counts, int* __restrict__ blk) {
    __shared__ int s[256];
    int base = blockIdx.x * 1024;
    int t = threadIdx.x;
    int sum = 0;
#pragma unroll
    for (int j = 0; j < 4; j++) {
        int i = base + t * 4 + j;
        if (i < N_NODES) sum += counts[i];
    }
    s[t] = sum;
    __syncthreads();
    for (int off = 128; off > 0; off >>= 1) {
        if (t < off) s[t] += s[t + off];
        __syncthreads();
    }
    if (t == 0) blk[blockIdx.x] = s[0];
}

// exclusive scan of chunk sums (parallel, one 128-thread block; nblk=98)
__global__ void k_scanB(int* __restrict__ blk, int nblk, int* __restrict__ row_ptr) {
    __shared__ int s[128];
    int t = threadIdx.x;
    int v = (t < nblk) ? blk[t] : 0;
    s[t] = v;
    __syncthreads();
    for (int off = 1; off < 128; off <<= 1) {
        int x = (t >= off) ? s[t - off] : 0;
        __syncthreads();
        s[t] += x;
        __syncthreads();
    }
    if (t < nblk) blk[t] = s[t] - v;  // exclusive
    if (t == 0) row_ptr[N_NODES] = s[nblk - 1];
}

// local scan + chunk offset -> row_ptr
__global__ void k_scanC(const int* __restrict__ counts, const int* __restrict__ blk,
                        int* __restrict__ row_ptr) {
    __shared__ int s[256];
    int base = blockIdx.x * 1024;
    int t = threadIdx.x;
    int local[4];
    int sum = 0;
#pragma unroll
    for (int j = 0; j < 4; j++) {
        int i = base + t * 4 + j;
        int v = (i < N_NODES) ? counts[i] : 0;
        local[j] = v;
        sum += v;
    }
    s[t] = sum;
    __syncthreads();
    for (int off = 1; off < 256; off <<= 1) {
        int v2 = (t >= off) ? s[t - off] : 0;
        __syncthreads();
        s[t] += v2;
        __syncthreads();
    }
    int excl = s[t] - sum + blk[blockIdx.x];
#pragma unroll
    for (int j = 0; j < 4; j++) {
        int i = base + t * 4 + j;
        if (i < N_NODES) {
            row_ptr[i] = excl;
            excl += local[j];
        }
    }
}

// atomic-free streaming scatter: slot = row_ptr[row] + pos[e]
__global__ void k_scatter(const int* __restrict__ rows, const int* __restrict__ cols,
                          const float* __restrict__ vals, const int* __restrict__ rp,
                          const int* __restrict__ pos, int2* __restrict__ edges) {
    int e = blockIdx.x * blockDim.x + threadIdx.x;
    if (e < NNZ) {
        int slot = rp[rows[e]] + pos[e];
        edges[slot] = make_int2(cols[e], __float_as_int(vals[e]));
    }
}

// ---------------- propagation ----------------

__global__ void k_initE(const float4* __restrict__ ue, const float4* __restrict__ ie,
                        float4* __restrict__ E, __half2* __restrict__ Eh2) {
    int i = blockIdx.x * blockDim.x + threadIdx.x;  // float4 index
    const int UQ = N_USERS * DIM / 4;   // 640000
    const int TQ = N_NODES * DIM / 4;   // 1600000
    float4 v;
    if (i < UQ) v = ue[i];
    else if (i < TQ) v = ie[i - UQ];
    else return;
    E[i] = v;
    Eh2[i * 2] = __floats2half2_rn(v.x, v.y);
    Eh2[i * 2 + 1] = __floats2half2_rn(v.z, v.w);
}

// Fused layer: per block 64 rows; phase 1 gather-SpMM (f16 E, f32 acc) into LDS
// bridge gs[64][68]; phase 2 MFMA transform -> leaky_relu -> l2norm, writes f32 E
// (in-place, own rows only) and f16 copy to Eh_out (ping-pong vs Eh_in).
// No __syncthreads needed: each wave owns its 16 rows end-to-end.
__global__ __launch_bounds__(256) void k_layer(const __half2* __restrict__ Eh_in,
                                               const int* __restrict__ rp,
                                               const int2* __restrict__ edges,
                                               float* __restrict__ E,
                                               __half* __restrict__ Eh_out,
                                               const float* __restrict__ W1,
                                               const float* __restrict__ W2) {
    __shared__ float gs[64][68];
    int t = threadIdx.x;
    int l = t & 63, w = t >> 6;
    int half = l >> 5, l32 = l & 31;
    int base = blockIdx.x * 64;

    // ---- phase 1: SpMM for this wave's 16 rows ----
    for (int i = 0; i < 16; i++) {
        int r = base + w * 16 + i;
        float2 acc = make_float2(0.f, 0.f);
        if (r < N_NODES) {
            int s = rp[r], e = rp[r + 1];
            int j = s;
            for (; j + 8 <= e; j += 8) {
                int eb = j + half * 4;
                int2 q0 = edges[eb], q1 = edges[eb + 1], q2 = edges[eb + 2], q3 = edges[eb + 3];
                float2 f0 = __half22float2(Eh_in[(size_t)q0.x * 32 + l32]);
                float2 f1 = __half22float2(Eh_in[(size_t)q1.x * 32 + l32]);
                float2 f2 = __half22float2(Eh_in[(size_t)q2.x * 32 + l32]);
                float2 f3 = __half22float2(Eh_in[(size_t)q3.x * 32 + l32]);
                float v0 = __int_as_float(q0.y), v1 = __int_as_float(q1.y);
                float v2 = __int_as_float(q2.y), v3 = __int_as_float(q3.y);
                acc.x = fmaf(v0, f0.x, acc.x); acc.y = fmaf(v0, f0.y, acc.y);
                acc.x = fmaf(v1, f1.x, acc.x); acc.y = fmaf(v1, f1.y, acc.y);
                acc.x = fmaf(v2, f2.x, acc.x); acc.y = fmaf(v2, f2.y, acc.y);
                acc.x = fmaf(v3, f3.x, acc.x); acc.y = fmaf(v3, f3.y, acc.y);
            }
            for (; j + 2 <= e; j += 2) {
                int2 q = edges[j + half];
                float2 f = __half22float2(Eh_in[(size_t)q.x * 32 + l32]);
                float v = __int_as_float(q.y);
                acc.x = fmaf(v, f.x, acc.x);
                acc.y = fmaf(v, f.y, acc.y);
            }
            if (j < e && half == 0) {
                int2 q = edges[j];
                float2 f = __half22float2(Eh_in[(size_t)q.x * 32 + l32]);
                float v = __int_as_float(q.y);
                acc.x = fmaf(v, f.x, acc.x);
                acc.y = fmaf(v, f.y, acc.y);
            }
        }
        acc.x += __shfl_xor(acc.x, 32);
        acc.y += __shfl_xor(acc.y, 32);
        if (half == 0) *(float2*)&gs[w * 16 + i][l32 * 2] = acc;
    }

    __builtin_amdgcn_sched_barrier(0);  // keep W-frag loads out of the gather phase

    // ---- phase 2: MFMA transform of the 16 rows ----
    int m = l & 15;
    int ko = (l >> 4) * 8;  // 0,8,16,24

    half8 b1[4][2], b2[4][2];
#pragma unroll
    for (int tt = 0; tt < 4; tt++)
#pragma unroll
        for (int c = 0; c < 2; c++)
#pragma unroll
            for (int jj = 0; jj < 8; jj++) {
                int k = c * 32 + ko + jj;
                b1[tt][c][jj] = (_Float16)W1[k * DIM + tt * 16 + m];
                b2[tt][c][jj] = (_Float16)W2[k * DIM + tt * 16 + m];
            }

    size_t rowm = (size_t)base + w * 16 + m;
    half8 a1[2], a2[2];
#pragma unroll
    for (int c = 0; c < 2; c++) {
        const float* pe = &E[rowm * DIM + c * 32 + ko];
        float4 e0 = *(const float4*)pe, e1 = *(const float4*)(pe + 4);
        float4 g0 = *(const float4*)&gs[w * 16 + m][c * 32 + ko];
        float4 g1 = *(const float4*)&gs[w * 16 + m][c * 32 + ko + 4];
        a1[c][0] = (_Float16)(e0.x + g0.x); a2[c][0] = (_Float16)(e0.x * g0.x);
        a1[c][1] = (_Float16)(e0.y + g0.y); a2[c][1] = (_Float16)(e0.y * g0.y);
        a1[c][2] = (_Float16)(e0.z + g0.z); a2[c][2] = (_Float16)(e0.z * g0.z);
        a1[c][3] = (_Float16)(e0.w + g0.w); a2[c][3] = (_Float16)(e0.w * g0.w);
        a1[c][4] = (_Float16)(e1.x + g1.x); a2[c][4] = (_Float16)(e1.x * g1.x);
        a1[c][5] = (_Float16)(e1.y + g1.y); a2[c][5] = (_Float16)(e1.y * g1.y);
        a1[c][6] = (_Float16)(e1.z + g1.z); a2[c][6] = (_Float16)(e1.z * g1.z);
        a1[c][7] = (_Float16)(e1.w + g1.w); a2[c][7] = (_Float16)(e1.w * g1.w);
    }

    f32x4 acc[4];
#pragma unroll
    for (int tt = 0; tt < 4; tt++) {
        acc[tt] = (f32x4){0.f, 0.f, 0.f, 0.f};
        acc[tt] = __builtin_amdgcn_mfma_f32_16x16x32_f16(a1[0], b1[tt][0], acc[tt], 0, 0, 0);
        acc[tt] = __builtin_amdgcn_mfma_f32_16x16x32_f16(a1[1], b1[tt][1], acc[tt], 0, 0, 0);
        acc[tt] = __builtin_amdgcn_mfma_f32_16x16x32_f16(a2[0], b2[tt][0], acc[tt], 0, 0, 0);
        acc[tt] = __builtin_amdgcn_mfma_f32_16x16x32_f16(a2[1], b2[tt][1], acc[tt], 0, 0, 0);
    }

    // epilogue: leaky-relu, per-row l2 norm (row = (l>>4)*4 + q, 16 lanes per row)
    float vv[4][4];
    float part[4];
#pragma unroll
    for (int q = 0; q < 4; q++) part[q] = 0.f;
#pragma unroll
    for (int tt = 0; tt < 4; tt++)
#pragma unroll
        for (int q = 0; q < 4; q++) {
            float v = acc[tt][q];
            v = v > 0.f ? v : NEG_SLOPE * v;
            vv[tt][q] = v;
            part[q] = fmaf(v, v, part[q]);
        }
#pragma unroll
    for (int q = 0; q < 4; q++) {
#pragma unroll
        for (int off = 1; off < 16; off <<= 1) part[q] += __shfl_xor(part[q], off);
        part[q] = fmaxf(sqrtf(part[q]), 1e-12f);
    }
#pragma unroll
    for (int tt = 0; tt < 4; tt++)
#pragma unroll
        for (int q = 0; q < 4; q++) {
            float o = vv[tt][q] / part[q];
            size_t row = (size_t)base + w * 16 + (l >> 4) * 4 + q;
            E[row * DIM + tt * 16 + m] = o;
            Eh_out[row * DIM + tt * 16 + m] = __float2half(o);
        }
}

// gather batch rows into u/i feature blocks
__global__ void k_gather(const float* __restrict__ E, const int* __restrict__ uids,
                         const int* __restrict__ iids, float* __restrict__ uf,
                         float* __restrict__ inf, int col0) {
    int gid = blockIdx.x * blockDim.x + threadIdx.x;
    int row = gid >> 6, lane = gid & 63;
    if (row < BATCH) {
        uf[row * 256 + col0 + lane] = E[(size_t)uids[row] * DIM + lane];
    } else if (row < 2 * BATCH) {
        int r = row - BATCH;
        inf[r * 256 + col0 + lane] = E[(size_t)(N_USERS + iids[r]) * DIM + lane];
    }
}

// ---------------- final scores: out = U @ I^T ----------------

__global__ __launch_bounds__(256) void k_score(const float* __restrict__ uf,
                                               const float* __restrict__ inf,
                                               float* __restrict__ out) {
    __shared__ float su[32][68];
    __shared__ float si[32][68];
    int t = threadIdx.x;
    int bx = blockIdx.x & 15, by = blockIdx.x >> 4;
    int tx = t & 15, ty = t >> 4;
    int lrow = t >> 2;
    int lk = (t & 3) * 8;
    float acc[4][4] = {};
    for (int kk = 0; kk < 256; kk += 32) {
        float4 a0 = *(const float4*)&uf[(by * 64 + lrow) * 256 + kk + lk];
        float4 a1 = *(const float4*)&uf[(by * 64 + lrow) * 256 + kk + lk + 4];
        float4 b0 = *(const float4*)&inf[(bx * 64 + lrow) * 256 + kk + lk];
        float4 b1 = *(const float4*)&inf[(bx * 64 + lrow) * 256 + kk + lk + 4];
        __syncthreads();
        su[lk + 0][lrow] = a0.x; su[lk + 1][lrow] = a0.y;
        su[lk + 2][lrow] = a0.z; su[lk + 3][lrow] = a0.w;
        su[lk + 4][lrow] = a1.x; su[lk + 5][lrow] = a1.y;
        su[lk + 6][lrow] = a1.z; su[lk + 7][lrow] = a1.w;
        si[lk + 0][lrow] = b0.x; si[lk + 1][lrow] = b0.y;
        si[lk + 2][lrow] = b0.z; si[lk + 3][lrow] = b0.w;
        si[lk + 4][lrow] = b1.x; si[lk + 5][lrow] = b1.y;
        si[lk + 6][lrow] = b1.z; si[lk + 7][lrow] = b1.w;
        __syncthreads();
#pragma unroll
        for (int k = 0; k < 32; k++) {
            const float* pu = &su[k][ty * 4];
            const float* pi = &si[k][tx * 4];
#pragma unroll
            for (int mi = 0; mi < 4; mi++)
#pragma unroll
                for (int ni = 0; ni < 4; ni++)
                    acc[mi][ni] = fmaf(pu[mi], pi[ni], acc[mi][ni]);
        }
    }
#pragma unroll
    for (int mi = 0; mi < 4; mi++)
#pragma unroll
        for (int ni = 0; ni < 4; ni++)
            out[(size_t)(by * 64 + ty * 4 + mi) * 1024 + bx * 64 + tx * 4 + ni] = acc[mi][ni];
}

// ---------------- launch ----------------

extern "C" void kernel_launch(void* const* d_in, const int* in_sizes, int n_in,
                              void* d_out, int out_size, void* d_ws, size_t ws_size,
                              hipStream_t stream) {
    const float* user_embed = (const float*)d_in[0];
    const float* item_embed = (const float*)d_in[1];
    const float* W1[3] = {(const float*)d_in[2], (const float*)d_in[3], (const float*)d_in[4]};
    const float* W2[3] = {(const float*)d_in[5], (const float*)d_in[6], (const float*)d_in[7]};
    const float* adj_vals = (const float*)d_in[8];
    const int* adj_rows = (const int*)d_in[9];
    const int* adj_cols = (const int*)d_in[10];
    const int* user_ids = (const int*)d_in[11];
    const int* item_ids = (const int*)d_in[12];
    float* out = (float*)d_out;

    // workspace carve-up (all 16B-aligned)
    float* E = (float*)d_ws;                          // NPAD*64 f32
    __half* Eh0 = (__half*)(E + (size_t)NPAD * DIM);  // NPAD*64 f16
    __half* Eh1 = Eh0 + (size_t)NPAD * DIM;           // NPAD*64 f16
    float* uf = (float*)(Eh1 + (size_t)NPAD * DIM);   // 256K f32
    float* inf = uf + BATCH * 256;                    // 256K f32
    int2* edges = (int2*)(inf + BATCH * 256);         // 1.2M int2
    int* pos = (int*)(edges + NNZ);                   // 1.2M int
    int* row_ptr = pos + NNZ;                         // 100001
    int* counts = row_ptr + (N_NODES + 1);            // 100000
    int* blk = counts + N_NODES;                      // 128

    const int NBLK = (N_NODES + 1023) / 1024;  // 98

    // CSR build (one atomic pass; scatter is atomic-free streaming)
    k_zero<<<(N_NODES + 255) / 256, 256, 0, stream>>>(counts, N_NODES);
    k_count<<<(NNZ + 255) / 256, 256, 0, stream>>>(adj_rows, counts, pos);
    k_scanA<<<NBLK, 256, 0, stream>>>(counts, blk);
    k_scanB<<<1, 128, 0, stream>>>(blk, NBLK, row_ptr);
    k_scanC<<<NBLK, 256, 0, stream>>>(counts, blk, row_ptr);
    k_scatter<<<(NNZ + 255) / 256, 256, 0, stream>>>(adj_rows, adj_cols, adj_vals,
                                                     row_ptr, pos, edges);

    // E init (f32 + f16 ping) + layer-0 gather
    k_initE<<<(N_NODES * DIM / 4 + 255) / 256, 256, 0, stream>>>(
        (const float4*)user_embed, (const float4*)item_embed, (float4*)E, (__half2*)Eh0);
    k_gather<<<(2 * BATCH * DIM) / 256, 256, 0, stream>>>(E, user_ids, item_ids, uf, inf, 0);

    // 3 fused layers, Eh ping-pong
    __half* hb[2] = {Eh0, Eh1};
    for (int l = 0; l < 3; l++) {
        k_layer<<<NPAD / 64, 256, 0, stream>>>((const __half2*)hb[l & 1], row_ptr, edges,
                                               E, hb[(l + 1) & 1], W1[l], W2[l]);
        k_gather<<<(2 * BATCH * DIM) / 256, 256, 0, stream>>>(E, user_ids, item_ids, uf, inf,
                                                              (l + 1) * 64);
    }

    // scores
    k_score<<<256, 256, 0, stream>>>(uf, inf, out);
}

// Round 11
// 397.377 us; speedup vs baseline: 1.2016x; 1.2016x over previous
//
#include <hip/hip_runtime.h>
#include <hip/hip_bf16.h>
#include <hip/hip_fp16.h>

#define N_USERS 40000
#define N_ITEMS 60000
#define N_NODES 100000
#define NPAD 100032  // padded to 64-row blocks for MFMA transform
#define DIM 64
#define NNZ 1200000
#define BATCH 1024
#define NEG_SLOPE 0.2f

typedef _Float16 half8 __attribute__((ext_vector_type(8)));
typedef float f32x4 __attribute__((ext_vector_type(4)));

// ---------------- CSR build ----------------

__global__ void k_zero(int* __restrict__ p, int n) {
    int i = blockIdx.x * blockDim.x + threadIdx.x;
    if (i < n) p[i] = 0;
}

// count + per-edge intra-row rank (pos). One atomic per edge.
__global__ void k_count(const int* __restrict__ rows, int* __restrict__ counts,
                        int* __restrict__ pos) {
    int e = blockIdx.x * blockDim.x + threadIdx.x;
    if (e < NNZ) pos[e] = atomicAdd(&counts[rows[e]], 1);
}

// per-chunk (1024 elems) sums
__global__ void k_scanA(const int* __restrict__ counts, int* __restrict__ blk) {
    __shared__ int s[256];
    int base = blockIdx.x * 1024;
    int t = threadIdx.x;
    int sum = 0;
#pragma unroll
    for (int j = 0; j < 4; j++) {
        int i = base + t * 4 + j;
        if (i < N_NODES) sum += counts[i];
    }
    s[t] = sum;
    __syncthreads();
    for (int off = 128; off > 0; off >>= 1) {
        if (t < off) s[t] += s[t + off];
        __syncthreads();
    }
    if (t == 0) blk[blockIdx.x] = s[0];
}

// exclusive scan of chunk sums (parallel, one 128-thread block; nblk=98)
__global__ void k_scanB(int* __restrict__ blk, int nblk, int* __restrict__ row_ptr) {
    __shared__ int s[128];
    int t = threadIdx.x;
    int v = (t < nblk) ? blk[t] : 0;
    s[t] = v;
    __syncthreads();
    for (int off = 1; off < 128; off <<= 1) {
        int x = (t >= off) ? s[t - off] : 0;
        __syncthreads();
        s[t] += x;
        __syncthreads();
    }
    if (t < nblk) blk[t] = s[t] - v;  // exclusive
    if (t == 0) row_ptr[N_NODES] = s[nblk - 1];
}

// local scan + chunk offset -> row_ptr
__global__ void k_scanC(const int* __restrict__ counts, const int* __restrict__ blk,
                        int* __restrict__ row_ptr) {
    __shared__ int s[256];
    int base = blockIdx.x * 1024;
    int t = threadIdx.x;
    int local[4];
    int sum = 0;
#pragma unroll
    for (int j = 0; j < 4; j++) {
        int i = base + t * 4 + j;
        int v = (i < N_NODES) ? counts[i] : 0;
        local[j] = v;
        sum += v;
    }
    s[t] = sum;
    __syncthreads();
    for (int off = 1; off < 256; off <<= 1) {
        int v2 = (t >= off) ? s[t - off] : 0;
        __syncthreads();
        s[t] += v2;
        __syncthreads();
    }
    int excl = s[t] - sum + blk[blockIdx.x];
#pragma unroll
    for (int j = 0; j < 4; j++) {
        int i = base + t * 4 + j;
        if (i < N_NODES) {
            row_ptr[i] = excl;
            excl += local[j];
        }
    }
}

// atomic-free streaming scatter: slot = row_ptr[row] + pos[e]
__global__ void k_scatter(const int* __restrict__ rows, const int* __restrict__ cols,
                          const float* __restrict__ vals, const int* __restrict__ rp,
                          const int* __restrict__ pos, int2* __restrict__ edges) {
    int e = blockIdx.x * blockDim.x + threadIdx.x;
    if (e < NNZ) {
        int slot = rp[rows[e]] + pos[e];
        edges[slot] = make_int2(cols[e], __float_as_int(vals[e]));
    }
}

// ---------------- propagation ----------------

__global__ void k_initE(const float4* __restrict__ ue, const float4* __restrict__ ie,
                        float4* __restrict__ E, __half2* __restrict__ Eh2) {
    int i = blockIdx.x * blockDim.x + threadIdx.x;  // float4 index
    const int UQ = N_USERS * DIM / 4;   // 640000
    const int TQ = N_NODES * DIM / 4;   // 1600000
    float4 v;
    if (i < UQ) v = ue[i];
    else if (i < TQ) v = ie[i - UQ];
    else return;
    E[i] = v;
    Eh2[i * 2] = __floats2half2_rn(v.x, v.y);
    Eh2[i * 2 + 1] = __floats2half2_rn(v.z, v.w);
}

// gather-side SpMM over f16 E copy: one wave per row; lane holds 2 dims (half2),
// lane halves process even/odd edges concurrently; f32 accumulate.
// Output G written as f16 into Gh2 (the NEXT Eh buffer — later overwritten by k_xform).
__global__ __launch_bounds__(256) void k_spmm(const __half2* __restrict__ Eh_in,
                                              const int* __restrict__ rp,
                                              const int2* __restrict__ edges,
                                              __half2* __restrict__ Gh2) {
    int gid = blockIdx.x * blockDim.x + threadIdx.x;
    int r = gid >> 6, lane = gid & 63;
    if (r >= N_NODES) return;
    int half = lane >> 5, l32 = lane & 31;
    int s = rp[r], e = rp[r + 1];
    float2 acc = make_float2(0.f, 0.f);
    int j = s;
    for (; j + 8 <= e; j += 8) {
        int eb = j + half * 4;
        int2 q0 = edges[eb], q1 = edges[eb + 1], q2 = edges[eb + 2], q3 = edges[eb + 3];
        float2 f0 = __half22float2(Eh_in[(size_t)q0.x * 32 + l32]);
        float2 f1 = __half22float2(Eh_in[(size_t)q1.x * 32 + l32]);
        float2 f2 = __half22float2(Eh_in[(size_t)q2.x * 32 + l32]);
        float2 f3 = __half22float2(Eh_in[(size_t)q3.x * 32 + l32]);
        float v0 = __int_as_float(q0.y), v1 = __int_as_float(q1.y);
        float v2 = __int_as_float(q2.y), v3 = __int_as_float(q3.y);
        acc.x = fmaf(v0, f0.x, acc.x); acc.y = fmaf(v0, f0.y, acc.y);
        acc.x = fmaf(v1, f1.x, acc.x); acc.y = fmaf(v1, f1.y, acc.y);
        acc.x = fmaf(v2, f2.x, acc.x); acc.y = fmaf(v2, f2.y, acc.y);
        acc.x = fmaf(v3, f3.x, acc.x); acc.y = fmaf(v3, f3.y, acc.y);
    }
    for (; j + 2 <= e; j += 2) {
        int2 q = edges[j + half];
        float2 f = __half22float2(Eh_in[(size_t)q.x * 32 + l32]);
        float v = __int_as_float(q.y);
        acc.x = fmaf(v, f.x, acc.x);
        acc.y = fmaf(v, f.y, acc.y);
    }
    if (j < e && half == 0) {  // odd tail edge
        int2 q = edges[j];
        float2 f = __half22float2(Eh_in[(size_t)q.x * 32 + l32]);
        float v = __int_as_float(q.y);
        acc.x = fmaf(v, f.x, acc.x);
        acc.y = fmaf(v, f.y, acc.y);
    }
    acc.x += __shfl_xor(acc.x, 32);
    acc.y += __shfl_xor(acc.y, 32);
    if (half == 0) Gh2[(size_t)r * 32 + l32] = __floats2half2_rn(acc.x, acc.y);
}

// MFMA transform: per wave, 16 rows x 64 outcols via 16x16x32 f16 MFMA.
//   side1=(E+G)@W1 + side2=(E*G)@W2 -> leaky_relu -> l2norm.
// GEh (no restrict): G read from it, new f16 E written over it. Safe: each wave
// reads only its own 16 rows (lockstep) before storing them. E updated in-place.
__global__ __launch_bounds__(256) void k_xform(float* __restrict__ E,
                                               __half* GEh,
                                               const float* __restrict__ W1,
                                               const float* __restrict__ W2) {
    int l = threadIdx.x & 63;
    int wv = threadIdx.x >> 6;
    int m = l & 15;
    int ko = (l >> 4) * 8;  // 0,8,16,24

    // W fragments: 4 n-tiles x 2 k-chunks x 2 mats in VGPRs (L2-resident loads)
    half8 b1[4][2], b2[4][2];
#pragma unroll
    for (int tt = 0; tt < 4; tt++)
#pragma unroll
        for (int c = 0; c < 2; c++)
#pragma unroll
            for (int jj = 0; jj < 8; jj++) {
                int k = c * 32 + ko + jj;
                b1[tt][c][jj] = (_Float16)W1[k * DIM + tt * 16 + m];
                b2[tt][c][jj] = (_Float16)W2[k * DIM + tt * 16 + m];
            }

    size_t base = (size_t)blockIdx.x * 64 + wv * 16;
    size_t rowm = base + m;

    half8 a1[2], a2[2];
#pragma unroll
    for (int c = 0; c < 2; c++) {
        const float* pe = &E[rowm * DIM + c * 32 + ko];
        float4 e0 = *(const float4*)pe, e1 = *(const float4*)(pe + 4);
        half8 gv = *(const half8*)&GEh[rowm * DIM + c * 32 + ko];
        float ef[8] = {e0.x, e0.y, e0.z, e0.w, e1.x, e1.y, e1.z, e1.w};
#pragma unroll
        for (int jj = 0; jj < 8; jj++) {
            float g = (float)gv[jj];
            a1[c][jj] = (_Float16)(ef[jj] + g);
            a2[c][jj] = (_Float16)(ef[jj] * g);
        }
    }

    f32x4 acc[4];
#pragma unroll
    for (int tt = 0; tt < 4; tt++) {
        acc[tt] = (f32x4){0.f, 0.f, 0.f, 0.f};
        acc[tt] = __builtin_amdgcn_mfma_f32_16x16x32_f16(a1[0], b1[tt][0], acc[tt], 0, 0, 0);
        acc[tt] = __builtin_amdgcn_mfma_f32_16x16x32_f16(a1[1], b1[tt][1], acc[tt], 0, 0, 0);
        acc[tt] = __builtin_amdgcn_mfma_f32_16x16x32_f16(a2[0], b2[tt][0], acc[tt], 0, 0, 0);
        acc[tt] = __builtin_amdgcn_mfma_f32_16x16x32_f16(a2[1], b2[tt][1], acc[tt], 0, 0, 0);
    }

    // epilogue: leaky-relu, per-row l2 norm (row = (l>>4)*4 + q, 16 lanes per row)
    float vv[4][4];
    float part[4];
#pragma unroll
    for (int q = 0; q < 4; q++) part[q] = 0.f;
#pragma unroll
    for (int tt = 0; tt < 4; tt++)
#pragma unroll
        for (int q = 0; q < 4; q++) {
            float v = acc[tt][q];
            v = v > 0.f ? v : NEG_SLOPE * v;
            vv[tt][q] = v;
            part[q] = fmaf(v, v, part[q]);
        }
#pragma unroll
    for (int q = 0; q < 4; q++) {
#pragma unroll
        for (int off = 1; off < 16; off <<= 1) part[q] += __shfl_xor(part[q], off);
        part[q] = fmaxf(sqrtf(part[q]), 1e-12f);
    }
#pragma unroll
    for (int tt = 0; tt < 4; tt++)
#pragma unroll
        for (int q = 0; q < 4; q++) {
            float o = vv[tt][q] / part[q];
            size_t row = base + (l >> 4) * 4 + q;
            E[row * DIM + tt * 16 + m] = o;
            GEh[row * DIM + tt * 16 + m] = __float2half(o);
        }
}

// gather batch rows into u/i feature blocks
__global__ void k_gather(const float* __restrict__ E, const int* __restrict__ uids,
                         const int* __restrict__ iids, float* __restrict__ uf,
                         float* __restrict__ inf, int col0) {
    int gid = blockIdx.x * blockDim.x + threadIdx.x;
    int row = gid >> 6, lane = gid & 63;
    if (row < BATCH) {
        uf[row * 256 + col0 + lane] = E[(size_t)uids[row] * DIM + lane];
    } else if (row < 2 * BATCH) {
        int r = row - BATCH;
        inf[r * 256 + col0 + lane] = E[(size_t)(N_USERS + iids[r]) * DIM + lane];
    }
}

// ---------------- final scores: out = U @ I^T ----------------

__global__ __launch_bounds__(256) void k_score(const float* __restrict__ uf,
                                               const float* __restrict__ inf,
                                               float* __restrict__ out) {
    __shared__ float su[32][68];
    __shared__ float si[32][68];
    int t = threadIdx.x;
    int bx = blockIdx.x & 15, by = blockIdx.x >> 4;
    int tx = t & 15, ty = t >> 4;
    int lrow = t >> 2;
    int lk = (t & 3) * 8;
    float acc[4][4] = {};
    for (int kk = 0; kk < 256; kk += 32) {
        float4 a0 = *(const float4*)&uf[(by * 64 + lrow) * 256 + kk + lk];
        float4 a1 = *(const float4*)&uf[(by * 64 + lrow) * 256 + kk + lk + 4];
        float4 b0 = *(const float4*)&inf[(bx * 64 + lrow) * 256 + kk + lk];
        float4 b1 = *(const float4*)&inf[(bx * 64 + lrow) * 256 + kk + lk + 4];
        __syncthreads();
        su[lk + 0][lrow] = a0.x; su[lk + 1][lrow] = a0.y;
        su[lk + 2][lrow] = a0.z; su[lk + 3][lrow] = a0.w;
        su[lk + 4][lrow] = a1.x; su[lk + 5][lrow] = a1.y;
        su[lk + 6][lrow] = a1.z; su[lk + 7][lrow] = a1.w;
        si[lk + 0][lrow] = b0.x; si[lk + 1][lrow] = b0.y;
        si[lk + 2][lrow] = b0.z; si[lk + 3][lrow] = b0.w;
        si[lk + 4][lrow] = b1.x; si[lk + 5][lrow] = b1.y;
        si[lk + 6][lrow] = b1.z; si[lk + 7][lrow] = b1.w;
        __syncthreads();
#pragma unroll
        for (int k = 0; k < 32; k++) {
            const float* pu = &su[k][ty * 4];
            const float* pi = &si[k][tx * 4];
#pragma unroll
            for (int mi = 0; mi < 4; mi++)
#pragma unroll
                for (int ni = 0; ni < 4; ni++)
                    acc[mi][ni] = fmaf(pu[mi], pi[ni], acc[mi][ni]);
        }
    }
#pragma unroll
    for (int mi = 0; mi < 4; mi++)
#pragma unroll
        for (int ni = 0; ni < 4; ni++)
            out[(size_t)(by * 64 + ty * 4 + mi) * 1024 + bx * 64 + tx * 4 + ni] = acc[mi][ni];
}

// ---------------- launch ----------------

extern "C" void kernel_launch(void* const* d_in, const int* in_sizes, int n_in,
                              void* d_out, int out_size, void* d_ws, size_t ws_size,
                              hipStream_t stream) {
    const float* user_embed = (const float*)d_in[0];
    const float* item_embed = (const float*)d_in[1];
    const float* W1[3] = {(const float*)d_in[2], (const float*)d_in[3], (const float*)d_in[4]};
    const float* W2[3] = {(const float*)d_in[5], (const float*)d_in[6], (const float*)d_in[7]};
    const float* adj_vals = (const float*)d_in[8];
    const int* adj_rows = (const int*)d_in[9];
    const int* adj_cols = (const int*)d_in[10];
    const int* user_ids = (const int*)d_in[11];
    const int* item_ids = (const int*)d_in[12];
    float* out = (float*)d_out;

    // workspace carve-up (all 16B-aligned)
    float* E = (float*)d_ws;                          // NPAD*64 f32
    __half* Eh0 = (__half*)(E + (size_t)NPAD * DIM);  // NPAD*64 f16
    __half* Eh1 = Eh0 + (size_t)NPAD * DIM;           // NPAD*64 f16
    float* uf = (float*)(Eh1 + (size_t)NPAD * DIM);   // 256K f32
    float* inf = uf + BATCH * 256;                    // 256K f32
    int2* edges = (int2*)(inf + BATCH * 256);         // 1.2M int2
    int* pos = (int*)(edges + NNZ);                   // 1.2M int
    int* row_ptr = pos + NNZ;                         // 100001
    int* counts = row_ptr + (N_NODES + 1);            // 100000
    int* blk = counts + N_NODES;                      // 128

    const int NBLK = (N_NODES + 1023) / 1024;  // 98

    // CSR build (one atomic pass; scatter is atomic-free streaming)
    k_zero<<<(N_NODES + 255) / 256, 256, 0, stream>>>(counts, N_NODES);
    k_count<<<(NNZ + 255) / 256, 256, 0, stream>>>(adj_rows, counts, pos);
    k_scanA<<<NBLK, 256, 0, stream>>>(counts, blk);
    k_scanB<<<1, 128, 0, stream>>>(blk, NBLK, row_ptr);
    k_scanC<<<NBLK, 256, 0, stream>>>(counts, blk, row_ptr);
    k_scatter<<<(NNZ + 255) / 256, 256, 0, stream>>>(adj_rows, adj_cols, adj_vals,
                                                     row_ptr, pos, edges);

    // E init (f32 + f16 ping) + layer-0 gather
    k_initE<<<(N_NODES * DIM / 4 + 255) / 256, 256, 0, stream>>>(
        (const float4*)user_embed, (const float4*)item_embed, (float4*)E, (__half2*)Eh0);
    k_gather<<<(2 * BATCH * DIM) / 256, 256, 0, stream>>>(E, user_ids, item_ids, uf, inf, 0);

    // 3 layers: spmm (f16 in, f16 G out into next Eh buf) -> MFMA xform (overwrites G with new Eh)
    __half* hb[2] = {Eh0, Eh1};
    for (int l = 0; l < 3; l++) {
        __half* cur = hb[l & 1];
        __half* nxt = hb[(l + 1) & 1];
        k_spmm<<<(N_NODES * DIM) / 256, 256, 0, stream>>>((const __half2*)cur, row_ptr, edges,
                                                          (__half2*)nxt);
        k_xform<<<NPAD / 64, 256, 0, stream>>>(E, nxt, W1[l], W2[l]);
        k_gather<<<(2 * BATCH * DIM) / 256, 256, 0, stream>>>(E, user_ids, item_ids, uf, inf,
                                                              (l + 1) * 64);
    }

    // scores
    k_score<<<256, 256, 0, stream>>>(uf, inf, out);
}

// Round 13
// 377.960 us; speedup vs baseline: 1.2633x; 1.0514x over previous
//
#include <hip/hip_runtime.h>
#include <hip/hip_bf16.h>
#include <hip/hip_fp16.h>

#define N_USERS 40000
#define N_ITEMS 60000
#define N_NODES 100000
#define NPAD 100032  // padded to 64-row blocks for MFMA transform
#define DIM 64
#define NNZ 1200000
#define BATCH 1024
#define NEG_SLOPE 0.2f
#define CSTRIDE 16  // one counter per 64B line (atomic line-chaining fix)

typedef _Float16 half8 __attribute__((ext_vector_type(8)));
typedef float f32x4 __attribute__((ext_vector_type(4)));

// ---------------- CSR build ----------------

__global__ void k_zero(int* __restrict__ p, int n) {
    int i = blockIdx.x * blockDim.x + threadIdx.x;
    if (i < n) p[i] = 0;
}

// count + per-edge intra-row rank (pos). One atomic per edge; padded counters
// (stride 16 ints = 64B) so each row's counter owns a full cache line.
__global__ void k_count(const int* __restrict__ rows, int* __restrict__ counts,
                        int* __restrict__ pos) {
    int e = blockIdx.x * blockDim.x + threadIdx.x;
    if (e < NNZ) pos[e] = atomicAdd(&counts[(size_t)rows[e] * CSTRIDE], 1);
}

// per-chunk (1024 rows) sums over padded counts
__global__ void k_scanA(const int* __restrict__ counts, int* __restrict__ blk) {
    __shared__ int s[256];
    int base = blockIdx.x * 1024;
    int t = threadIdx.x;
    int sum = 0;
#pragma unroll
    for (int j = 0; j < 4; j++) {
        int i = base + t * 4 + j;
        if (i < N_NODES) sum += counts[(size_t)i * CSTRIDE];
    }
    s[t] = sum;
    __syncthreads();
    for (int off = 128; off > 0; off >>= 1) {
        if (t < off) s[t] += s[t + off];
        __syncthreads();
    }
    if (t == 0) blk[blockIdx.x] = s[0];
}

// exclusive scan of chunk sums (parallel, one 128-thread block; nblk=98)
__global__ void k_scanB(int* __restrict__ blk, int nblk, int* __restrict__ row_ptr) {
    __shared__ int s[128];
    int t = threadIdx.x;
    int v = (t < nblk) ? blk[t] : 0;
    s[t] = v;
    __syncthreads();
    for (int off = 1; off < 128; off <<= 1) {
        int x = (t >= off) ? s[t - off] : 0;
        __syncthreads();
        s[t] += x;
        __syncthreads();
    }
    if (t < nblk) blk[t] = s[t] - v;  // exclusive
    if (t == 0) row_ptr[N_NODES] = s[nblk - 1];
}

// local scan + chunk offset -> row_ptr (reads padded counts)
__global__ void k_scanC(const int* __restrict__ counts, const int* __restrict__ blk,
                        int* __restrict__ row_ptr) {
    __shared__ int s[256];
    int base = blockIdx.x * 1024;
    int t = threadIdx.x;
    int local[4];
    int sum = 0;
#pragma unroll
    for (int j = 0; j < 4; j++) {
        int i = base + t * 4 + j;
        int v = (i < N_NODES) ? counts[(size_t)i * CSTRIDE] : 0;
        local[j] = v;
        sum += v;
    }
    s[t] = sum;
    __syncthreads();
    for (int off = 1; off < 256; off <<= 1) {
        int v2 = (t >= off) ? s[t - off] : 0;
        __syncthreads();
        s[t] += v2;
        __syncthreads();
    }
    int excl = s[t] - sum + blk[blockIdx.x];
#pragma unroll
    for (int j = 0; j < 4; j++) {
        int i = base + t * 4 + j;
        if (i < N_NODES) {
            row_ptr[i] = excl;
            excl += local[j];
        }
    }
}

// atomic-free streaming scatter: slot = row_ptr[row] + pos[e]
__global__ void k_scatter(const int* __restrict__ rows, const int* __restrict__ cols,
                          const float* __restrict__ vals, const int* __restrict__ rp,
                          const int* __restrict__ pos, int2* __restrict__ edges) {
    int e = blockIdx.x * blockDim.x + threadIdx.x;
    if (e < NNZ) {
        int slot = rp[rows[e]] + pos[e];
        edges[slot] = make_int2(cols[e], __float_as_int(vals[e]));
    }
}

// ---------------- propagation ----------------

__global__ void k_initE(const float4* __restrict__ ue, const float4* __restrict__ ie,
                        float4* __restrict__ E, __half2* __restrict__ Eh2) {
    int i = blockIdx.x * blockDim.x + threadIdx.x;  // float4 index
    const int UQ = N_USERS * DIM / 4;   // 640000
    const int TQ = N_NODES * DIM / 4;   // 1600000
    float4 v;
    if (i < UQ) v = ue[i];
    else if (i < TQ) v = ie[i - UQ];
    else return;
    E[i] = v;
    Eh2[i * 2] = __floats2half2_rn(v.x, v.y);
    Eh2[i * 2 + 1] = __floats2half2_rn(v.z, v.w);
}

// gather-side SpMM over f16 E copy: one wave per row; lane holds 2 dims (half2),
// lane halves process even/odd edge quads. Masked always-8-wide iterations:
// every row issues its edge loads in ceil(deg/8) FULLY PARALLEL batches (no
// serial 2-edge tail — that tail was the latency chain for deg<16 rows).
__global__ __launch_bounds__(256) void k_spmm(const __half2* __restrict__ Eh_in,
                                              const int* __restrict__ rp,
                                              const int2* __restrict__ edges,
                                              __half2* __restrict__ Gh2) {
    int gid = blockIdx.x * blockDim.x + threadIdx.x;
    int r = gid >> 6, lane = gid & 63;
    if (r >= N_NODES) return;
    int half = lane >> 5, l32 = lane & 31;
    int s = rp[r], e = rp[r + 1];
    int cnt = e - s;
    float2 acc = make_float2(0.f, 0.f);
    for (int jb = 0; jb < cnt; jb += 8) {
        int b0 = jb + half * 4;
#pragma unroll
        for (int k = 0; k < 4; k++) {
            int off = b0 + k;
            int2 q = edges[s + min(off, cnt - 1)];
            float2 f = __half22float2(Eh_in[(size_t)q.x * 32 + l32]);
            float v = (off < cnt) ? __int_as_float(q.y) : 0.f;
            acc.x = fmaf(v, f.x, acc.x);
            acc.y = fmaf(v, f.y, acc.y);
        }
    }
    acc.x += __shfl_xor(acc.x, 32);
    acc.y += __shfl_xor(acc.y, 32);
    if (half == 0) Gh2[(size_t)r * 32 + l32] = __floats2half2_rn(acc.x, acc.y);
}

// MFMA transform: per wave, 16 rows x 64 outcols via 16x16x32 f16 MFMA.
//   side1=(E+G)@W1 + side2=(E*G)@W2 -> leaky_relu -> l2norm.
// GEh (no restrict): G read from it, new f16 E written over it. Safe: each wave
// reads only its own 16 rows (lockstep) before storing them. E updated in-place.
__global__ __launch_bounds__(256) void k_xform(float* __restrict__ E,
                                               __half* GEh,
                                               const float* __restrict__ W1,
                                               const float* __restrict__ W2) {
    int l = threadIdx.x & 63;
    int wv = threadIdx.x >> 6;
    int m = l & 15;
    int ko = (l >> 4) * 8;  // 0,8,16,24

    // W fragments: 4 n-tiles x 2 k-chunks x 2 mats in VGPRs (L2-resident loads)
    half8 b1[4][2], b2[4][2];
#pragma unroll
    for (int tt = 0; tt < 4; tt++)
#pragma unroll
        for (int c = 0; c < 2; c++)
#pragma unroll
            for (int jj = 0; jj < 8; jj++) {
                int k = c * 32 + ko + jj;
                b1[tt][c][jj] = (_Float16)W1[k * DIM + tt * 16 + m];
                b2[tt][c][jj] = (_Float16)W2[k * DIM + tt * 16 + m];
            }

    size_t base = (size_t)blockIdx.x * 64 + wv * 16;
    size_t rowm = base + m;

    half8 a1[2], a2[2];
#pragma unroll
    for (int c = 0; c < 2; c++) {
        const float* pe = &E[rowm * DIM + c * 32 + ko];
        float4 e0 = *(const float4*)pe, e1 = *(const float4*)(pe + 4);
        half8 gv = *(const half8*)&GEh[rowm * DIM + c * 32 + ko];
        float ef[8] = {e0.x, e0.y, e0.z, e0.w, e1.x, e1.y, e1.z, e1.w};
#pragma unroll
        for (int jj = 0; jj < 8; jj++) {
            float g = (float)gv[jj];
            a1[c][jj] = (_Float16)(ef[jj] + g);
            a2[c][jj] = (_Float16)(ef[jj] * g);
        }
    }

    f32x4 acc[4];
#pragma unroll
    for (int tt = 0; tt < 4; tt++) {
        acc[tt] = (f32x4){0.f, 0.f, 0.f, 0.f};
        acc[tt] = __builtin_amdgcn_mfma_f32_16x16x32_f16(a1[0], b1[tt][0], acc[tt], 0, 0, 0);
        acc[tt] = __builtin_amdgcn_mfma_f32_16x16x32_f16(a1[1], b1[tt][1], acc[tt], 0, 0, 0);
        acc[tt] = __builtin_amdgcn_mfma_f32_16x16x32_f16(a2[0], b2[tt][0], acc[tt], 0, 0, 0);
        acc[tt] = __builtin_amdgcn_mfma_f32_16x16x32_f16(a2[1], b2[tt][1], acc[tt], 0, 0, 0);
    }

    // epilogue: leaky-relu, per-row l2 norm (row = (l>>4)*4 + q, 16 lanes per row)
    float vv[4][4];
    float part[4];
#pragma unroll
    for (int q = 0; q < 4; q++) part[q] = 0.f;
#pragma unroll
    for (int tt = 0; tt < 4; tt++)
#pragma unroll
        for (int q = 0; q < 4; q++) {
            float v = acc[tt][q];
            v = v > 0.f ? v : NEG_SLOPE * v;
            vv[tt][q] = v;
            part[q] = fmaf(v, v, part[q]);
        }
#pragma unroll
    for (int q = 0; q < 4; q++) {
#pragma unroll
        for (int off = 1; off < 16; off <<= 1) part[q] += __shfl_xor(part[q], off);
        part[q] = fmaxf(sqrtf(part[q]), 1e-12f);
    }
#pragma unroll
    for (int tt = 0; tt < 4; tt++)
#pragma unroll
        for (int q = 0; q < 4; q++) {
            float o = vv[tt][q] / part[q];
            size_t row = base + (l >> 4) * 4 + q;
            E[row * DIM + tt * 16 + m] = o;
            GEh[row * DIM + tt * 16 + m] = __float2half(o);
        }
}

// gather batch rows into u/i feature blocks
__global__ void k_gather(const float* __restrict__ E, const int* __restrict__ uids,
                         const int* __restrict__ iids, float* __restrict__ uf,
                         float* __restrict__ inf, int col0) {
    int gid = blockIdx.x * blockDim.x + threadIdx.x;
    int row = gid >> 6, lane = gid & 63;
    if (row < BATCH) {
        uf[row * 256 + col0 + lane] = E[(size_t)uids[row] * DIM + lane];
    } else if (row < 2 * BATCH) {
        int r = row - BATCH;
        inf[r * 256 + col0 + lane] = E[(size_t)(N_USERS + iids[r]) * DIM + lane];
    }
}

// ---------------- final scores: out = U @ I^T ----------------

__global__ __launch_bounds__(256) void k_score(const float* __restrict__ uf,
                                               const float* __restrict__ inf,
                                               float* __restrict__ out) {
    __shared__ float su[32][68];
    __shared__ float si[32][68];
    int t = threadIdx.x;
    int bx = blockIdx.x & 15, by = blockIdx.x >> 4;
    int tx = t & 15, ty = t >> 4;
    int lrow = t >> 2;
    int lk = (t & 3) * 8;
    float acc[4][4] = {};
    for (int kk = 0; kk < 256; kk += 32) {
        float4 a0 = *(const float4*)&uf[(by * 64 + lrow) * 256 + kk + lk];
        float4 a1 = *(const float4*)&uf[(by * 64 + lrow) * 256 + kk + lk + 4];
        float4 b0 = *(const float4*)&inf[(bx * 64 + lrow) * 256 + kk + lk];
        float4 b1 = *(const float4*)&inf[(bx * 64 + lrow) * 256 + kk + lk + 4];
        __syncthreads();
        su[lk + 0][lrow] = a0.x; su[lk + 1][lrow] = a0.y;
        su[lk + 2][lrow] = a0.z; su[lk + 3][lrow] = a0.w;
        su[lk + 4][lrow] = a1.x; su[lk + 5][lrow] = a1.y;
        su[lk + 6][lrow] = a1.z; su[lk + 7][lrow] = a1.w;
        si[lk + 0][lrow] = b0.x; si[lk + 1][lrow] = b0.y;
        si[lk + 2][lrow] = b0.z; si[lk + 3][lrow] = b0.w;
        si[lk + 4][lrow] = b1.x; si[lk + 5][lrow] = b1.y;
        si[lk + 6][lrow] = b1.z; si[lk + 7][lrow] = b1.w;
        __syncthreads();
#pragma unroll
        for (int k = 0; k < 32; k++) {
            const float* pu = &su[k][ty * 4];
            const float* pi = &si[k][tx * 4];
#pragma unroll
            for (int mi = 0; mi < 4; mi++)
#pragma unroll
                for (int ni = 0; ni < 4; ni++)
                    acc[mi][ni] = fmaf(pu[mi], pi[ni], acc[mi][ni]);
        }
    }
#pragma unroll
    for (int mi = 0; mi < 4; mi++)
#pragma unroll
        for (int ni = 0; ni < 4; ni++)
            out[(size_t)(by * 64 + ty * 4 + mi) * 1024 + bx * 64 + tx * 4 + ni] = acc[mi][ni];
}

// ---------------- launch ----------------

extern "C" void kernel_launch(void* const* d_in, const int* in_sizes, int n_in,
                              void* d_out, int out_size, void* d_ws, size_t ws_size,
                              hipStream_t stream) {
    const float* user_embed = (const float*)d_in[0];
    const float* item_embed = (const float*)d_in[1];
    const float* W1[3] = {(const float*)d_in[2], (const float*)d_in[3], (const float*)d_in[4]};
    const float* W2[3] = {(const float*)d_in[5], (const float*)d_in[6], (const float*)d_in[7]};
    const float* adj_vals = (const float*)d_in[8];
    const int* adj_rows = (const int*)d_in[9];
    const int* adj_cols = (const int*)d_in[10];
    const int* user_ids = (const int*)d_in[11];
    const int* item_ids = (const int*)d_in[12];
    float* out = (float*)d_out;

    // workspace carve-up (all 16B-aligned)
    float* E = (float*)d_ws;                          // NPAD*64 f32
    __half* Eh0 = (__half*)(E + (size_t)NPAD * DIM);  // NPAD*64 f16
    __half* Eh1 = Eh0 + (size_t)NPAD * DIM;           // NPAD*64 f16
    float* uf = (float*)(Eh1 + (size_t)NPAD * DIM);   // 256K f32
    float* inf = uf + BATCH * 256;                    // 256K f32
    int2* edges = (int2*)(inf + BATCH * 256);         // 1.2M int2
    int* pos = (int*)(edges + NNZ);                   // 1.2M int
    int* row_ptr = pos + NNZ;                         // 100001
    int* counts = row_ptr + (N_NODES + 1);            // 100000*16 (padded, 6.4MB)
    int* blk = counts + (size_t)N_NODES * CSTRIDE;    // 128

    const int NBLK = (N_NODES + 1023) / 1024;  // 98

    // CSR build (one atomic pass on padded counters; scatter is atomic-free)
    k_zero<<<(N_NODES * CSTRIDE + 255) / 256, 256, 0, stream>>>(counts, N_NODES * CSTRIDE);
    k_count<<<(NNZ + 255) / 256, 256, 0, stream>>>(adj_rows, counts, pos);
    k_scanA<<<NBLK, 256, 0, stream>>>(counts, blk);
    k_scanB<<<1, 128, 0, stream>>>(blk, NBLK, row_ptr);
    k_scanC<<<NBLK, 256, 0, stream>>>(counts, blk, row_ptr);
    k_scatter<<<(NNZ + 255) / 256, 256, 0, stream>>>(adj_rows, adj_cols, adj_vals,
                                                     row_ptr, pos, edges);

    // E init (f32 + f16 ping) + layer-0 gather
    k_initE<<<(N_NODES * DIM / 4 + 255) / 256, 256, 0, stream>>>(
        (const float4*)user_embed, (const float4*)item_embed, (float4*)E, (__half2*)Eh0);
    k_gather<<<(2 * BATCH * DIM) / 256, 256, 0, stream>>>(E, user_ids, item_ids, uf, inf, 0);

    // 3 layers: spmm (f16 in, f16 G out into next Eh buf) -> MFMA xform (overwrites G with new Eh)
    __half* hb[2] = {Eh0, Eh1};
    for (int l = 0; l < 3; l++) {
        __half* cur = hb[l & 1];
        __half* nxt = hb[(l + 1) & 1];
        k_spmm<<<(N_NODES * DIM) / 256, 256, 0, stream>>>((const __half2*)cur, row_ptr, edges,
                                                          (__half2*)nxt);
        k_xform<<<NPAD / 64, 256, 0, stream>>>(E, nxt, W1[l], W2[l]);
        k_gather<<<(2 * BATCH * DIM) / 256, 256, 0, stream>>>(E, user_ids, item_ids, uf, inf,
                                                              (l + 1) * 64);
    }

    // scores
    k_score<<<256, 256, 0, stream>>>(uf, inf, out);
}